// Round 1
// baseline (142.727 us; speedup 1.0000x reference)
//
#include <hip/hip_runtime.h>
#include <math.h>

#define B_ROWS   512
#define T_SAMP   32768
#define N_FRAME  128
#define CHUNK    16
#define TPB      256
#define TILE     (TPB*CHUNK)      // 4096
#define NTILE    (T_SAMP/TILE)    // 8
#define A_BLOCKS_PER_ROW 32       // 1024 samples per block (256 thr * 4)

#define POS_SCALE (127.0f/32767.0f)

struct Aff { float m00,m01,m10,m11,v0,v1; };

__device__ __forceinline__ Aff compose(const Aff& a, const Aff& b) { // a AFTER b
    Aff r;
    r.m00 = a.m00*b.m00 + a.m01*b.m10;
    r.m01 = a.m00*b.m01 + a.m01*b.m11;
    r.m10 = a.m10*b.m00 + a.m11*b.m10;
    r.m11 = a.m10*b.m01 + a.m11*b.m11;
    r.v0  = a.m00*b.v0  + a.m01*b.v1 + a.v0;
    r.v1  = a.m10*b.v0  + a.m11*b.v1 + a.v1;
    return r;
}

// Stage one row's per-frame coeffs {a1,a2,b0,b1,b2} into LDS (tanh mapping applied).
__device__ __forceinline__ void stage_coeffs(const float* __restrict__ logits, int b,
                                             float* lds_coef) {
    int tid = threadIdx.x;
    if (tid < N_FRAME) {
        const float* p = logits + ((size_t)b*N_FRAME + tid)*5;
        float l0=p[0], l1=p[1], c2=p[2], c3=p[3], c4=p[4];
        const float sf = 0.999f; // 1 - STABILITY_EPS
        float a1  = 2.0f*tanhf(l0)*sf;
        float a1a = fabsf(a1);
        float a2  = 0.5f*((2.0f - a1a)*tanhf(l1)*sf + a1a);
        float* q = lds_coef + tid*5;
        q[0]=a1; q[1]=a2; q[2]=c2; q[3]=c3; q[4]=c4;
    }
}

__global__ __launch_bounds__(TPB)
void acid_kernel(const float* __restrict__ x, const float* __restrict__ logits,
                 float* __restrict__ yout, float* __restrict__ aout,
                 float* __restrict__ bout) {
    __shared__ float lds_coef[N_FRAME*5];              // 2560 B
    __shared__ float lds_x[TPB*(CHUNK+1)];             // 17408 B (padded: stride 17)
    __shared__ float lds_state[TPB*2];                 // 2048 B
    __shared__ float lds_agg[4*6];                     // 96 B

    int tid = threadIdx.x;

    if (blockIdx.x < B_ROWS) {
        // ---------------- IIR+FIR scan path: one block per row ----------------
        int b = blockIdx.x;
        int lane = tid & 63, wv = tid >> 6;
        stage_coeffs(logits, b, lds_coef);
        const float* xrow = x + (size_t)b*T_SAMP;
        float* yrow = yout + (size_t)b*T_SAMP;
        float c0 = 0.f, c1 = 0.f;   // carry state (y_{-1}, y_{-2}) entering the tile

        for (int tile = 0; tile < NTILE; ++tile) {
            int tbase = tile*TILE;
            __syncthreads();  // staging vs previous writeout (and coeff stage on tile 0)
            // ---- stage x tile into padded LDS (coalesced float4 global reads) ----
            #pragma unroll
            for (int it = 0; it < 4; ++it) {
                int s = it*1024 + tid*4;
                float4 v = *(const float4*)(xrow + tbase + s);
                int c = s >> 4, e = s & 15;
                float* dst = lds_x + c*(CHUNK+1) + e;
                dst[0]=v.x; dst[1]=v.y; dst[2]=v.z; dst[3]=v.w;
            }
            __syncthreads();
            // ---- upsweep: affine map of this thread's 16-sample chunk ----
            int t0g = tbase + tid*CHUNK;
            const float* myx = lds_x + tid*(CHUNK+1);
            Aff p; p.m00=1.f; p.m01=0.f; p.m10=0.f; p.m11=1.f; p.v0=0.f; p.v1=0.f;
            #pragma unroll
            for (int n = 0; n < CHUNK; ++n) {
                int t = t0g + n;
                float pos = t*POS_SCALE;
                int lo = (int)pos; if (lo > 126) lo = 126;
                float w = pos - (float)lo, om = 1.0f - w;
                const float* fa = lds_coef + lo*5;
                float a1 = fa[0]*om + fa[5]*w;
                float a2 = fa[1]*om + fa[6]*w;
                float xn = myx[n];
                float t00 = -a1*p.m00 - a2*p.m10;
                float t01 = -a1*p.m01 - a2*p.m11;
                p.m10 = p.m00; p.m11 = p.m01; p.m00 = t00; p.m01 = t01;
                float tv = xn - a1*p.v0 - a2*p.v1;
                p.v1 = p.v0; p.v0 = tv;
            }
            // ---- intra-wave inclusive scan of affine maps ----
            #pragma unroll
            for (int d = 1; d < 64; d <<= 1) {
                Aff o;
                o.m00 = __shfl_up(p.m00, d); o.m01 = __shfl_up(p.m01, d);
                o.m10 = __shfl_up(p.m10, d); o.m11 = __shfl_up(p.m11, d);
                o.v0  = __shfl_up(p.v0,  d); o.v1  = __shfl_up(p.v1,  d);
                if (lane >= d) p = compose(p, o);
            }
            if (lane == 63) {
                float* g = lds_agg + wv*6;
                g[0]=p.m00; g[1]=p.m01; g[2]=p.m10; g[3]=p.m11; g[4]=p.v0; g[5]=p.v1;
            }
            __syncthreads();
            for (int j = wv-1; j >= 0; --j) {
                const float* g = lds_agg + j*6;
                Aff o; o.m00=g[0]; o.m01=g[1]; o.m10=g[2]; o.m11=g[3]; o.v0=g[4]; o.v1=g[5];
                p = compose(p, o);
            }
            // inclusive state after this chunk (with carry applied)
            float s0 = p.m00*c0 + p.m01*c1 + p.v0;
            float s1 = p.m10*c0 + p.m11*c1 + p.v1;
            lds_state[tid*2] = s0; lds_state[tid*2+1] = s1;
            __syncthreads();
            float y1, y2;
            if (tid == 0) { y1 = c0; y2 = c1; }
            else { y1 = lds_state[(tid-1)*2]; y2 = lds_state[(tid-1)*2+1]; }
            float nc0 = lds_state[TPB*2-2], nc1 = lds_state[TPB*2-1];
            // ---- downsweep: replay chunk with true init state, fuse FIR ----
            float* myxy = lds_x + tid*(CHUNK+1);
            #pragma unroll
            for (int n = 0; n < CHUNK; ++n) {
                int t = t0g + n;
                float pos = t*POS_SCALE;
                int lo = (int)pos; if (lo > 126) lo = 126;
                float w = pos - (float)lo, om = 1.0f - w;
                const float* fa = lds_coef + lo*5;
                float a1  = fa[0]*om + fa[5]*w;
                float a2  = fa[1]*om + fa[6]*w;
                float b0  = fa[2]*om + fa[7]*w;
                float b1f = fa[3]*om + fa[8]*w;
                float b2f = fa[4]*om + fa[9]*w;
                float xn = myxy[n];
                float y  = xn - a1*y1 - a2*y2;
                float o  = b0*y + b1f*y1 + b2f*y2;
                myxy[n] = o;
                y2 = y1; y1 = y;
            }
            __syncthreads();
            // ---- coalesced writeout of y_ab ----
            #pragma unroll
            for (int it = 0; it < 4; ++it) {
                int s = it*1024 + tid*4;
                int c = s >> 4, e = s & 15;
                const float* src = lds_x + c*(CHUNK+1) + e;
                *(float4*)(yrow + tbase + s) = make_float4(src[0], src[1], src[2], src[3]);
            }
            c0 = nc0; c1 = nc1;
        }
    } else {
        // ---------------- coeff expansion path: a_full / b_coeff writer ----------------
        int ab = blockIdx.x - B_ROWS;
        int b = ab >> 5;                 // 32 blocks per row
        int blk = ab & 31;
        stage_coeffs(logits, b, lds_coef);
        __syncthreads();
        int t0 = (blk*TPB + tid) * 4;    // 4 consecutive samples per thread
        float av[12], bv[12];
        #pragma unroll
        for (int s = 0; s < 4; ++s) {
            int t = t0 + s;
            float pos = t*POS_SCALE;
            int lo = (int)pos; if (lo > 126) lo = 126;
            float w = pos - (float)lo, om = 1.0f - w;
            const float* fa = lds_coef + lo*5;
            av[s*3+0] = 1.0f;
            av[s*3+1] = fa[0]*om + fa[5]*w;
            av[s*3+2] = fa[1]*om + fa[6]*w;
            bv[s*3+0] = fa[2]*om + fa[7]*w;
            bv[s*3+1] = fa[3]*om + fa[8]*w;
            bv[s*3+2] = fa[4]*om + fa[9]*w;
        }
        size_t base = ((size_t)b*T_SAMP + t0) * 3;
        float4* pa = (float4*)(aout + base);
        float4* pb = (float4*)(bout + base);
        #pragma unroll
        for (int k = 0; k < 3; ++k) {
            pa[k] = make_float4(av[k*4+0], av[k*4+1], av[k*4+2], av[k*4+3]);
            pb[k] = make_float4(bv[k*4+0], bv[k*4+1], bv[k*4+2], bv[k*4+3]);
        }
    }
}

extern "C" void kernel_launch(void* const* d_in, const int* in_sizes, int n_in,
                              void* d_out, int out_size, void* d_ws, size_t ws_size,
                              hipStream_t stream) {
    const float* x      = (const float*)d_in[0];   // [512, 32768] f32
    const float* logits = (const float*)d_in[1];   // [512, 128, 5] f32
    float* yout = (float*)d_out;                           // [512, 32768]
    float* aout = yout + (size_t)B_ROWS*T_SAMP;            // [512, 32768, 3]
    float* bout = aout + (size_t)B_ROWS*T_SAMP*3;          // [512, 32768, 3]
    int grid = B_ROWS + B_ROWS*A_BLOCKS_PER_ROW;  // scan blocks first for overlap
    hipLaunchKernelGGL(acid_kernel, dim3(grid), dim3(TPB), 0, stream,
                       x, logits, yout, aout, bout);
}

// Round 2
// 112.963 us; speedup vs baseline: 1.2635x; 1.2635x over previous
//
#include <hip/hip_runtime.h>
#include <math.h>

#define B_ROWS   512
#define T_SAMP   32768
#define N_FRAME  128
#define CHUNK    16
#define TPB      256
#define TILE     (TPB*CHUNK)      // 4096
#define NTILE    (T_SAMP/TILE)    // 8
#define A_BLOCKS_PER_ROW 32       // 1024 samples per block (256 thr * 4)

#define POS_SCALE (127.0f/32767.0f)

struct Aff { float m00,m01,m10,m11,v0,v1; };

__device__ __forceinline__ Aff compose(const Aff& a, const Aff& b) { // a AFTER b
    Aff r;
    r.m00 = a.m00*b.m00 + a.m01*b.m10;
    r.m01 = a.m00*b.m01 + a.m01*b.m11;
    r.m10 = a.m10*b.m00 + a.m11*b.m10;
    r.m11 = a.m10*b.m01 + a.m11*b.m11;
    r.v0  = a.m00*b.v0  + a.m01*b.v1 + a.v0;
    r.v1  = a.m10*b.v0  + a.m11*b.v1 + a.v1;
    return r;
}

// Stage one row's per-frame coeffs {a1,a2,b0,b1,b2} into LDS (tanh mapping applied).
__device__ __forceinline__ void stage_coeffs(const float* __restrict__ logits, int b,
                                             float* lds_coef) {
    int tid = threadIdx.x;
    if (tid < N_FRAME) {
        const float* p = logits + ((size_t)b*N_FRAME + tid)*5;
        float l0=p[0], l1=p[1], c2=p[2], c3=p[3], c4=p[4];
        const float sf = 0.999f; // 1 - STABILITY_EPS
        float a1  = 2.0f*tanhf(l0)*sf;
        float a1a = fabsf(a1);
        float a2  = 0.5f*((2.0f - a1a)*tanhf(l1)*sf + a1a);
        float* q = lds_coef + tid*5;
        q[0]=a1; q[1]=a2; q[2]=c2; q[3]=c3; q[4]=c4;
    }
}

__global__ __launch_bounds__(TPB)
void acid_kernel(const float* __restrict__ x, const float* __restrict__ logits,
                 float* __restrict__ yout, float* __restrict__ aout,
                 float* __restrict__ bout) {
    __shared__ float lds_coef[N_FRAME*5];                       // 2560 B
    __shared__ __align__(16) float lds_x[TPB*(CHUNK+1)];        // 17408 B (padded: stride 17)
    __shared__ float lds_state[TPB*2];                          // 2048 B
    __shared__ float lds_agg[4*6];                              // 96 B

    int tid = threadIdx.x;

    if (blockIdx.x < B_ROWS) {
        // ---------------- IIR+FIR scan path: one block per row ----------------
        int b = blockIdx.x;
        int lane = tid & 63, wv = tid >> 6;
        stage_coeffs(logits, b, lds_coef);
        const float* xrow = x + (size_t)b*T_SAMP;
        float* yrow = yout + (size_t)b*T_SAMP;
        float c0 = 0.f, c1 = 0.f;   // carry state (y_{-1}, y_{-2}) entering the tile

        for (int tile = 0; tile < NTILE; ++tile) {
            int tbase = tile*TILE;
            __syncthreads();  // staging vs previous writeout (and coeff stage on tile 0)
            // ---- stage x tile into padded LDS (coalesced float4 global reads) ----
            #pragma unroll
            for (int it = 0; it < 4; ++it) {
                int s = it*1024 + tid*4;
                float4 v = *(const float4*)(xrow + tbase + s);
                int c = s >> 4, e = s & 15;
                float* dst = lds_x + c*(CHUNK+1) + e;
                dst[0]=v.x; dst[1]=v.y; dst[2]=v.z; dst[3]=v.w;
            }
            __syncthreads();
            // ---- upsweep: affine map of this thread's 16-sample chunk ----
            int t0g = tbase + tid*CHUNK;
            const float* myx = lds_x + tid*(CHUNK+1);
            Aff p; p.m00=1.f; p.m01=0.f; p.m10=0.f; p.m11=1.f; p.v0=0.f; p.v1=0.f;
            #pragma unroll
            for (int n = 0; n < CHUNK; ++n) {
                int t = t0g + n;
                float pos = t*POS_SCALE;
                int lo = (int)pos; if (lo > 126) lo = 126;
                float w = pos - (float)lo, om = 1.0f - w;
                const float* fa = lds_coef + lo*5;
                float a1 = fa[0]*om + fa[5]*w;
                float a2 = fa[1]*om + fa[6]*w;
                float xn = myx[n];
                float t00 = -a1*p.m00 - a2*p.m10;
                float t01 = -a1*p.m01 - a2*p.m11;
                p.m10 = p.m00; p.m11 = p.m01; p.m00 = t00; p.m01 = t01;
                float tv = xn - a1*p.v0 - a2*p.v1;
                p.v1 = p.v0; p.v0 = tv;
            }
            // ---- intra-wave inclusive scan of affine maps ----
            #pragma unroll
            for (int d = 1; d < 64; d <<= 1) {
                Aff o;
                o.m00 = __shfl_up(p.m00, d); o.m01 = __shfl_up(p.m01, d);
                o.m10 = __shfl_up(p.m10, d); o.m11 = __shfl_up(p.m11, d);
                o.v0  = __shfl_up(p.v0,  d); o.v1  = __shfl_up(p.v1,  d);
                if (lane >= d) p = compose(p, o);
            }
            if (lane == 63) {
                float* g = lds_agg + wv*6;
                g[0]=p.m00; g[1]=p.m01; g[2]=p.m10; g[3]=p.m11; g[4]=p.v0; g[5]=p.v1;
            }
            __syncthreads();
            for (int j = wv-1; j >= 0; --j) {
                const float* g = lds_agg + j*6;
                Aff o; o.m00=g[0]; o.m01=g[1]; o.m10=g[2]; o.m11=g[3]; o.v0=g[4]; o.v1=g[5];
                p = compose(p, o);
            }
            // inclusive state after this chunk (with carry applied)
            float s0 = p.m00*c0 + p.m01*c1 + p.v0;
            float s1 = p.m10*c0 + p.m11*c1 + p.v1;
            lds_state[tid*2] = s0; lds_state[tid*2+1] = s1;
            __syncthreads();
            float y1, y2;
            if (tid == 0) { y1 = c0; y2 = c1; }
            else { y1 = lds_state[(tid-1)*2]; y2 = lds_state[(tid-1)*2+1]; }
            float nc0 = lds_state[TPB*2-2], nc1 = lds_state[TPB*2-1];
            // ---- downsweep: replay chunk with true init state, fuse FIR ----
            float* myxy = lds_x + tid*(CHUNK+1);
            #pragma unroll
            for (int n = 0; n < CHUNK; ++n) {
                int t = t0g + n;
                float pos = t*POS_SCALE;
                int lo = (int)pos; if (lo > 126) lo = 126;
                float w = pos - (float)lo, om = 1.0f - w;
                const float* fa = lds_coef + lo*5;
                float a1  = fa[0]*om + fa[5]*w;
                float a2  = fa[1]*om + fa[6]*w;
                float b0  = fa[2]*om + fa[7]*w;
                float b1f = fa[3]*om + fa[8]*w;
                float b2f = fa[4]*om + fa[9]*w;
                float xn = myxy[n];
                float y  = xn - a1*y1 - a2*y2;
                float o  = b0*y + b1f*y1 + b2f*y2;
                myxy[n] = o;
                y2 = y1; y1 = y;
            }
            __syncthreads();
            // ---- coalesced writeout of y_ab ----
            #pragma unroll
            for (int it = 0; it < 4; ++it) {
                int s = it*1024 + tid*4;
                int c = s >> 4, e = s & 15;
                const float* src = lds_x + c*(CHUNK+1) + e;
                *(float4*)(yrow + tbase + s) = make_float4(src[0], src[1], src[2], src[3]);
            }
            c0 = nc0; c1 = nc1;
        }
    } else {
        // ---------------- coeff expansion path: a_full / b_coeff writer ----------------
        int ab = blockIdx.x - B_ROWS;
        int b = ab >> 5;                 // 32 blocks per row
        int blk = ab & 31;
        stage_coeffs(logits, b, lds_coef);
        __syncthreads();
        int t0 = (blk*TPB + tid) * 4;    // 4 consecutive samples per thread
        float av[12], bv[12];
        #pragma unroll
        for (int s = 0; s < 4; ++s) {
            int t = t0 + s;
            float pos = t*POS_SCALE;
            int lo = (int)pos; if (lo > 126) lo = 126;
            float w = pos - (float)lo, om = 1.0f - w;
            const float* fa = lds_coef + lo*5;
            av[s*3+0] = 1.0f;
            av[s*3+1] = fa[0]*om + fa[5]*w;
            av[s*3+2] = fa[1]*om + fa[6]*w;
            bv[s*3+0] = fa[2]*om + fa[7]*w;
            bv[s*3+1] = fa[3]*om + fa[8]*w;
            bv[s*3+2] = fa[4]*om + fa[9]*w;
        }
        // LDS-staged, fully coalesced writeout: block region = 1024 samples = 3072
        // floats = 768 float4 per array. Stage a-tile then b-tile through lds_x.
        float4* s4 = (float4*)lds_x;
        size_t rowbase = ((size_t)b*T_SAMP + (size_t)blk*(TPB*4))*3;
        float4* pa4 = (float4*)(aout + rowbase);
        float4* pb4 = (float4*)(bout + rowbase);
        // a_full: ds_write_b128 at 48B lane stride (2-way bank alias = free)
        s4[tid*3+0] = make_float4(av[0],av[1],av[2], av[3]);
        s4[tid*3+1] = make_float4(av[4],av[5],av[6], av[7]);
        s4[tid*3+2] = make_float4(av[8],av[9],av[10],av[11]);
        __syncthreads();
        #pragma unroll
        for (int k = 0; k < 3; ++k)   // lane-contiguous 1024B per wave store
            pa4[k*TPB + tid] = s4[k*TPB + tid];
        __syncthreads();
        // b_coeff
        s4[tid*3+0] = make_float4(bv[0],bv[1],bv[2], bv[3]);
        s4[tid*3+1] = make_float4(bv[4],bv[5],bv[6], bv[7]);
        s4[tid*3+2] = make_float4(bv[8],bv[9],bv[10],bv[11]);
        __syncthreads();
        #pragma unroll
        for (int k = 0; k < 3; ++k)
            pb4[k*TPB + tid] = s4[k*TPB + tid];
    }
}

extern "C" void kernel_launch(void* const* d_in, const int* in_sizes, int n_in,
                              void* d_out, int out_size, void* d_ws, size_t ws_size,
                              hipStream_t stream) {
    const float* x      = (const float*)d_in[0];   // [512, 32768] f32
    const float* logits = (const float*)d_in[1];   // [512, 128, 5] f32
    float* yout = (float*)d_out;                           // [512, 32768]
    float* aout = yout + (size_t)B_ROWS*T_SAMP;            // [512, 32768, 3]
    float* bout = aout + (size_t)B_ROWS*T_SAMP*3;          // [512, 32768, 3]
    int grid = B_ROWS + B_ROWS*A_BLOCKS_PER_ROW;  // scan blocks first for overlap
    hipLaunchKernelGGL(acid_kernel, dim3(grid), dim3(TPB), 0, stream,
                       x, logits, yout, aout, bout);
}